// Round 6
// baseline (157.860 us; speedup 1.0000x reference)
//
#include <hip/hip_runtime.h>
#include <hip/hip_fp16.h>

// SGConvolution: out = A @ (A @ x), A sparse COO (edge_row sorted).
// N=100000, E=1600000, D=64.
//
// R8 -> R9: 2 rows per gather instruction (dword loads), halves split.
//  - R8 (EPW32, 2x waves) was NEUTRAL -> not TLP/serial-chain-bound.
//    Remaining suspects: VMEM instruction rate, outstanding-load depth,
//    or scattered-line request rate. This round halves instruction count
//    and doubles in-flight depth while keeping line count constant (the
//    controlled experiment between those theories).
//  - Half-wave A (lanes 0-31) owns edges start..start+31; half B owns
//    start+32..start+63. Lane (half,m) loads uint = features {2m,2m+1}
//    of its half's current edge row: one global_load_dword covers TWO
//    full 128-B rows, each half dense-contiguous. 32 loads issued
//    upfront (32 outstanding; compiler emits counted vmcnt per use).
//  - Metadata broadcast per step via ds_bpermute (addr = 128*half + 4p);
//    row compare per-lane but half-uniform -> flushes always have a full
//    32-lane contiguous half active (TCC line-merge preserved, R7 lesson).
//  - fp32 flush does a 4-shuffle in-register transpose so both atomic
//    instructions cover contiguous 128-B spans (no strided lanes).
//  - prep (cast x->fp16 + zero h16b + zero out) and fp16 pk-atomic
//    intermediate carried over.

#define N_NODES 100000
#define N_EDGES 1600000
#define D_FEAT  64
#define EPW     64    // edges per wave (32 per half); 25000 waves exactly

#define N_ELEM   (N_NODES * D_FEAT)          // 6,400,000 features
#define N_CAST   (N_ELEM / 4)                // float4 cast tasks
#define N_Z16    (N_ELEM / 8)                // 16B zero tasks (h16b, 12.8 MB)
#define N_ZOUT   (N_ELEM / 4)                // 16B zero tasks (out, 25.6 MB)
#define PREP_TASKS (N_CAST + N_Z16 + N_ZOUT) // 4,000,000 -> 15625 blocks

__device__ __forceinline__ int bperm(int baddr, int off, int v) {
    return __builtin_amdgcn_ds_bpermute(baddr + off, v);
}

// fp32 flush with in-register transpose: lane (H,m) holds features
// {2m,2m+1}; redistribute so instr 1 writes features 0..31 (contiguous
// 128 B) and instr 2 features 32..63. Exec is always a full 32-lane half
// (row changes are half-uniform), so shuffle sources are in-half.
__device__ __forceinline__ void flush_f32(float* o, int row, int lane,
                                          float ax, float ay) {
    const int m = lane & 31;
    const int H = lane & 32;
    const float sx = __shfl(ax, H + (m >> 1));
    const float sy = __shfl(ay, H + (m >> 1));
    const float tx = __shfl(ax, H + 16 + (m >> 1));
    const float ty = __shfl(ay, H + 16 + (m >> 1));
    const float vA = (m & 1) ? sy : sx;          // feature m
    const float vB = (m & 1) ? ty : tx;          // feature m+32
    atomicAdd(&o[(size_t)row * D_FEAT + m], vA);
    atomicAdd(&o[(size_t)row * D_FEAT + 32 + m], vB);
}

template <bool HALF_OUT>
__device__ __forceinline__ void flush(void* outp, int row, int lane,
                                      float& ax, float& ay) {
    if constexpr (HALF_OUT) {
        // 32 lanes x 4 B contiguous pk-atomics (dense 128 B -> line-merged)
        __half2* o = (__half2*)outp;
        unsafeAtomicAdd(&o[(size_t)row * (D_FEAT / 2) + (lane & 31)],
                        __floats2half2_rn(ax, ay));
    } else {
        flush_f32((float*)outp, row, lane, ax, ay);
    }
    ax = 0.f; ay = 0.f;
}

template <bool HALF_OUT>
__global__ __launch_bounds__(256) void sg_spmm(
    const __half* __restrict__ h,          // [N, 64] fp16 feature table
    const int*    __restrict__ erow,       // [E] sorted destination rows
    const int*    __restrict__ ecol,       // [E] source cols
    const float*  __restrict__ eval,       // [E] edge weights
    void*         __restrict__ outp)       // [N, 64] pre-zeroed fp16 or fp32
{
    const int lane  = threadIdx.x & 63;
    const int wave  = (int)((blockIdx.x * blockDim.x + threadIdx.x) >> 6);
    const int start = wave * EPW;          // grid sized exactly; no tail
    const int m     = lane & 31;           // feature pair index (feat 2m,2m+1)
    const int baddr = (lane & 32) * 4;     // bpermute base: lane 32*half

    // Coalesced preload of this wave's 64 edge triples (lane i = edge start+i).
    const int   r_v = erow[start + lane];
    const int   c_v = ecol[start + lane];
    const float w_v = eval[start + lane];

    // Issue all 32 paired gathers upfront: step p covers edges
    // start+p (half A) and start+32+p (half B); each half reads its row
    // as 32 lanes x 4 B = dense 128 B.
    uint g[32];
#pragma unroll
    for (int p = 0; p < 32; ++p) {
        const int cc = bperm(baddr, 4 * p, c_v);             // per-half col
        g[p] = *((const uint*)(h + (size_t)cc * D_FEAT) + m);
    }

    int   cur_r = bperm(baddr, 0, r_v);    // per-half current row
    float ax = 0.f, ay = 0.f;

#pragma unroll
    for (int p = 0; p < 32; ++p) {
        const int rn = bperm(baddr, 4 * p, r_v);
        if (rn != cur_r) {                 // half-uniform, rare (sorted rows)
            flush<HALF_OUT>(outp, cur_r, lane, ax, ay);
            cur_r = rn;
        }
        const float ww = __uint_as_float(
            (unsigned)bperm(baddr, 4 * p, (int)__float_as_uint(w_v)));
        const float2 f = __half22float2(__builtin_bit_cast(__half2, g[p]));
        ax = fmaf(ww, f.x, ax);
        ay = fmaf(ww, f.y, ay);
    }
    flush<HALF_OUT>(outp, cur_r, lane, ax, ay);
}

// Fused bookkeeping: cast x -> h16a (fp16), zero h16b (spmm1 atomic target),
// zero out (spmm2 atomic target). One dispatch replaces 2 memsets + 2 casts.
__global__ __launch_bounds__(256) void prep(
    const float* __restrict__ x,
    __half*      __restrict__ h16a,
    __half*      __restrict__ h16b,
    float*       __restrict__ out)
{
    const int i = blockIdx.x * blockDim.x + threadIdx.x;
    if (i < N_CAST) {
        const float4 v = ((const float4*)x)[i];
        const __half2 a = __floats2half2_rn(v.x, v.y);
        const __half2 b = __floats2half2_rn(v.z, v.w);
        uint2 u;
        u.x = __builtin_bit_cast(unsigned int, a);
        u.y = __builtin_bit_cast(unsigned int, b);
        ((uint2*)h16a)[i] = u;                       // single 8B store
    } else if (i < N_CAST + N_Z16) {
        ((uint4*)h16b)[i - N_CAST] = make_uint4(0u, 0u, 0u, 0u);
    } else {
        ((float4*)out)[i - (N_CAST + N_Z16)] = make_float4(0.f, 0.f, 0.f, 0.f);
    }
}

extern "C" void kernel_launch(void* const* d_in, const int* in_sizes, int n_in,
                              void* d_out, int out_size, void* d_ws, size_t ws_size,
                              hipStream_t stream) {
    const float* x    = (const float*)d_in[0];
    const int*   erow = (const int*)  d_in[1];
    const int*   ecol = (const int*)  d_in[2];
    const float* eval = (const float*)d_in[3];
    float*       out  = (float*)d_out;

    // ws layout: h16a [0, 12.8M) | h16b [12.8M, 25.6M)
    __half* h16a = (__half*)d_ws;
    __half* h16b = h16a + N_ELEM;

    const int threads     = 256;
    const int prep_blocks = PREP_TASKS / threads;             // 15625 exactly
    const int spmm_blocks = (N_EDGES / EPW) * 64 / threads;   // 6250 exactly

    prep<<<prep_blocks, threads, 0, stream>>>(x, h16a, h16b, out);
    sg_spmm<true ><<<spmm_blocks, threads, 0, stream>>>(h16a, erow, ecol, eval, h16b);
    sg_spmm<false><<<spmm_blocks, threads, 0, stream>>>(h16b, erow, ecol, eval, out);
}